// Round 6
// baseline (81.024 us; speedup 1.0000x reference)
//
#include <hip/hip_runtime.h>
#include <hip/hip_bf16.h>
#include <cstdint>

#define BATCH 4
#define CDIM 256
#define NTOK 4096
#define IDIM 128

typedef __attribute__((ext_vector_type(4))) float f32x4;
typedef __attribute__((ext_vector_type(16))) float f32x16;
typedef __attribute__((ext_vector_type(8))) short short8;

static __device__ __forceinline__ unsigned cvt_pk(float lo, float hi) {
  unsigned r;
  asm("v_cvt_pk_bf16_f32 %0, %1, %2" : "=v"(r) : "v"(lo), "v"(hi));
  return r;
}
static __device__ __forceinline__ float bf2f(unsigned short u) {
  union { unsigned u; float f; } v;
  v.u = (unsigned)u << 16;
  return v.f;
}
static __device__ __forceinline__ float exp2_f(float x) {
#if __has_builtin(__builtin_amdgcn_exp2f)
  return __builtin_amdgcn_exp2f(x);
#else
  return exp2f(x);
#endif
}
// async global->LDS, 16B per lane. LDS dest = wave-uniform base + lane*16.
static __device__ __forceinline__ void gl16(const void* g, void* l) {
  __builtin_amdgcn_global_load_lds(
      (const __attribute__((address_space(1))) void*)g,
      (__attribute__((address_space(3))) void*)l, 16, 0, 0);
}

// ---------------------------------------------------------------------------
// Phase 0: cast weights fp32 -> bf16, into MFMA-fragment-order layouts.
//  proj p (theta/phi/g):  Wb[((p*32 + (c>>3))*128 + i)*8 + (c&7)] = w[i][c]
//    (theta additionally scaled by log2(e) -> softmax runs in base 2)
//  wo: Wb[98304 + ((i>>3)*256 + c)*8 + (i&7)] = wo[c][i]
// ---------------------------------------------------------------------------
__global__ __launch_bounds__(256) void cast_w_kernel(
    const float* __restrict__ wt, const float* __restrict__ wp,
    const float* __restrict__ wg, const float* __restrict__ wo,
    unsigned short* __restrict__ Wb)
{
  int id = blockIdx.x * 256 + threadIdx.x;   // 0..32767
  if (id < 24576) {
    int pidx = id >> 13;
    int rem = id & 8191;
    int i = rem >> 6, c4 = (rem & 63) * 4;
    const float* src = pidx == 0 ? wt : pidx == 1 ? wp : wg;
    float4 v = *(const float4*)&src[i * 256 + c4];
    float s = (pidx == 0) ? 1.4426950408889634f : 1.0f;
    uint2 u = make_uint2(cvt_pk(v.x * s, v.y * s), cvt_pk(v.z * s, v.w * s));
    *(uint2*)&Wb[(((size_t)pidx * 32 + (c4 >> 3)) * 128 + i) * 8 + (c4 & 7)] = u;
  } else {
    int rem = id - 24576;
    int c = rem >> 5, i4 = (rem & 31) * 4;
    float4 v = *(const float4*)&wo[c * 128 + i4];
    uint2 u = make_uint2(cvt_pk(v.x, v.y), cvt_pk(v.z, v.w));
    *(uint2*)&Wb[98304 + (((size_t)(i4 >> 3) * 256 + c) * 8) + (i4 & 7)] = u;
  }
}

// ---------------------------------------------------------------------------
// Phase 1: QKV projection, MFMA (unchanged).
// ---------------------------------------------------------------------------
__global__ __launch_bounds__(768) void qkv_kernel(
    const float* __restrict__ x, const unsigned short* __restrict__ Wb,
    unsigned short* __restrict__ Q, unsigned short* __restrict__ K,
    unsigned short* __restrict__ Vt)
{
  __shared__ __align__(16) unsigned short xt[64 * 256];
  __shared__ __align__(16) unsigned short sc[8][16 * 128];

  const int b = blockIdx.y;
  const int n0 = blockIdx.x * 64;
  const int t = threadIdx.x;
  const float* xb = x + (size_t)b * CDIM * NTOK;

  for (int it = 0; it < 3; ++it) {
    int u = it * 768 + t;
    if (u < 2048) {
      int c0 = (u >> 4) * 2;
      int n4 = (u & 15) * 4;
      float4 va = *(const float4*)&xb[(size_t)c0 * NTOK + n0 + n4];
      float4 vb = *(const float4*)&xb[(size_t)(c0 + 1) * NTOK + n0 + n4];
      const float* pa = (const float*)&va;
      const float* pb = (const float*)&vb;
#pragma unroll
      for (int j = 0; j < 4; ++j) {
        int n = n4 + j;
        unsigned pk = cvt_pk(pa[j], pb[j]);
        *(unsigned*)((char*)xt + n * 512 + ((c0 * 2) ^ ((n & 15) << 4))) = pk;
      }
    }
  }
  __syncthreads();

  const int lane = t & 63;
  const int wv = __builtin_amdgcn_readfirstlane(t >> 6);
  const int nsub = wv & 3, proj = wv >> 2;
  const int cl = lane & 15, g = lane >> 4;

  f32x4 acc[8];
#pragma unroll
  for (int i = 0; i < 8; ++i) acc[i] = (f32x4){0.f, 0.f, 0.f, 0.f};

  const int nrow = nsub * 16 + cl;
  const int swz = (nrow & 15) << 4;
#pragma unroll
  for (int kc = 0; kc < 8; ++kc) {
    int cb = kc * 32 + g * 8;
    short8 af = *(const short8*)((const char*)xt + nrow * 512 + ((cb * 2) ^ swz));
#pragma unroll
    for (int is = 0; is < 8; ++is) {
      short8 bf = *(const short8*)&Wb[(((size_t)proj * 32 + kc * 4 + g) * 128 +
                                       is * 16 + cl) * 8];
      acc[is] = __builtin_amdgcn_mfma_f32_16x16x32_bf16(af, bf, acc[is], 0, 0, 0);
    }
  }

  if (proj < 2) {
    unsigned short* scw = sc[wv];
#pragma unroll
    for (int is = 0; is < 8; ++is)
#pragma unroll
      for (int r = 0; r < 4; ++r) {
        int nl = g * 4 + r;
        int i2 = (is * 16 + cl) * 2;
        *(unsigned short*)((char*)scw + nl * 256 + (i2 ^ ((nl & 15) << 4))) =
            (unsigned short)cvt_pk(acc[is][r], 0.f);
      }
    unsigned short* dst = (proj == 0 ? Q : K) +
        ((size_t)b * NTOK + n0 + nsub * 16) * IDIM;
    int nr = lane >> 2;
    int swr = (nr & 15) << 4;
#pragma unroll
    for (int j = 0; j < 4; ++j) {
      int ch = (lane & 3) + 4 * j;
      short8 v = *(const short8*)((const char*)scw + nr * 256 + ((ch * 16) ^ swr));
      *(short8*)&dst[(size_t)nr * IDIM + ch * 8] = v;
    }
  } else {
    unsigned short* dstV = Vt + (size_t)b * IDIM * NTOK + n0 + nsub * 16 + g * 4;
#pragma unroll
    for (int is = 0; is < 8; ++is) {
      uint2 u = make_uint2(cvt_pk(acc[is][0], acc[is][1]),
                           cvt_pk(acc[is][2], acc[is][3]));
      *(uint2*)&dstV[(size_t)(is * 16 + cl) * NTOK] = u;
    }
  }
}

// ---------------------------------------------------------------------------
// Phase 2: flash attention v6. Counted-vmcnt pipeline (T3/T4), depth matched
// to consumption order: K 3-buffer (2-iter window), V 2-buffer (~1.5-iter).
// Issue stream [K0 V0 K1] | iter t: V(t+1), K(t+2) -> constant waits:
//   top of iter t:  vmcnt(8)  => K(t) landed;  barrier; issue; sched_barrier.
//   before PV:      vmcnt(12) => V(t) landed;  barrier.
// LDS 40KB/block -> exactly 4 blocks/CU (160KB), grid 1024, no tail.
// ---------------------------------------------------------------------------
__global__ __launch_bounds__(128, 2) void attn_kernel(
    const unsigned short* __restrict__ Q, const unsigned short* __restrict__ K,
    const unsigned short* __restrict__ Vt, unsigned short* __restrict__ Op,
    float2* __restrict__ ML)
{
  __shared__ __align__(16) unsigned short kls[3][32 * 128];  // 24KB
  __shared__ __align__(16) unsigned short vls[2][128 * 32];  // 16KB

  const int bid = blockIdx.x;                  // bid&7 = XCD
  const int b = (bid >> 1) & 3;                // batch pinned to an XCD pair
  const int ms = (bid >> 3) & 3;               // m-split
  const int nblk = (bid >> 5) + (bid & 1) * 32;
  const int t = threadIdx.x;
  const int lane = t & 63;
  const int n0 = nblk * 64 + ((t >> 6) << 5);  // wave's 32 n-cols
  const int c32 = lane & 31, hl = lane >> 5;
  const int p = t;                             // 0..127 staging id

  const unsigned short* Kb = K + (size_t)b * NTOK * IDIM;
  const unsigned short* Vb = Vt + (size_t)b * IDIM * NTOK;

  // Q fragments (B operand, 32x32x16): col=n (lane&31), k=i
  const unsigned short* Qp = Q + ((size_t)b * NTOK + n0 + c32) * IDIM + hl * 8;
  short8 q[8];
#pragma unroll
  for (int kc = 0; kc < 8; ++kc) q[kc] = *(const short8*)(Qp + kc * 16);

  // loop-invariant LDS byte offsets -----------------------------------------
  int koff[8];
#pragma unroll
  for (int kc = 0; kc < 8; ++kc)
    koff[kc] = c32 * 256 + ((((kc * 2 + hl) ^ (c32 & 7))) << 4);
  int voff[8];
#pragma unroll
  for (int it = 0; it < 4; ++it)
#pragma unroll
    for (int kt = 0; kt < 2; ++kt) {
      int rp = it * 16 + (c32 >> 1);
      voff[it * 2 + kt] =
          rp * 128 + ((((c32 & 1) * 4 + kt * 2 + hl) ^ (rp & 7)) << 4);
    }
  // loop-invariant staging offsets (element offsets into K/V, LDS byte offs)
  int kgo[4], vgo[4], lofs[4];
#pragma unroll
  for (int u = 0; u < 4; ++u) {
    int idx = p + 128 * u;
    lofs[u] = idx * 16;
    int r = idx >> 4, ch = idx & 15;
    kgo[u] = r * IDIM + ((ch ^ (r & 7)) * 8);
    int rp = idx >> 3, pp = idx & 7;
    int s = pp ^ (rp & 7);
    vgo[u] = (rp * 2 + (s >> 2)) * NTOK + (s & 3) * 8;
  }

  f32x16 o[4];
#pragma unroll
  for (int it = 0; it < 4; ++it)
#pragma unroll
    for (int e = 0; e < 16; ++e) o[it][e] = 0.f;
  float M = -3.0e38f, L = 0.f;

#define STAGE_K(cb, m0_)                                                      \
  {                                                                           \
    const unsigned short* Kit = Kb + (size_t)(m0_)*IDIM;                      \
    _Pragma("unroll")                                                         \
    for (int u = 0; u < 4; ++u)                                               \
      gl16(Kit + kgo[u], (char*)kls[cb] + lofs[u]);                           \
  }
#define STAGE_V(cb, m0_)                                                      \
  {                                                                           \
    const unsigned short* Vit = Vb + (m0_);                                   \
    _Pragma("unroll")                                                         \
    for (int u = 0; u < 4; ++u)                                               \
      gl16(Vit + vgo[u], (char*)vls[cb] + lofs[u]);                           \
  }

  const int mbase = ms * 1024;
  // drain Q-fragment loads so vmcnt arithmetic below is exact
  asm volatile("s_waitcnt vmcnt(0)" ::: "memory");
  // prologue stream: K0, V0, K1   (12 outstanding)
  STAGE_K(0, mbase)
  STAGE_V(0, mbase)
  STAGE_K(1, mbase + 32)

  int kr = 0;   // kls slot holding tile t
  int vr = 0;   // vls slot holding tile t

  for (int tt = 0; tt < 32; ++tt) {
    // K(t) landed (8 newer loads outstanding); both waves agree after barrier.
    asm volatile("s_waitcnt vmcnt(8)\n\ts_barrier" ::: "memory");
    {
      int mv = mbase + (tt >= 31 ? 31 : tt + 1) * 32;  // clamped dummies keep
      int mk = mbase + (tt >= 30 ? 31 : tt + 2) * 32;  // vmcnt counts uniform
      STAGE_V(vr ^ 1, mv)
      STAGE_K(kr == 0 ? 2 : kr - 1, mk)
      __builtin_amdgcn_sched_barrier(0);
    }

    const char* kbuf = (const char*)kls[kr];
    const char* vbuf = (const char*)vls[vr];

    // ---- St = K . Q^T (32m x 32n), two independent 4-MFMA chains ----------
    f32x16 sa, sb;
#pragma unroll
    for (int e = 0; e < 16; ++e) { sa[e] = 0.f; sb[e] = 0.f; }
    __builtin_amdgcn_s_setprio(1);
#pragma unroll
    for (int kc = 0; kc < 4; ++kc) {
      short8 ka = *(const short8*)(kbuf + koff[kc]);
      short8 kb2 = *(const short8*)(kbuf + koff[kc + 4]);
      sa = __builtin_amdgcn_mfma_f32_32x32x16_bf16(ka, q[kc], sa, 0, 0, 0);
      sb = __builtin_amdgcn_mfma_f32_32x32x16_bf16(kb2, q[kc + 4], sb, 0, 0, 0);
    }
    __builtin_amdgcn_s_setprio(0);
    f32x16 st = sa + sb;

    // ---- online softmax over m (base-2; col n = lane&31), tree-reduced ----
    float mx[8];
#pragma unroll
    for (int j = 0; j < 8; ++j) mx[j] = fmaxf(st[j], st[j + 8]);
#pragma unroll
    for (int j = 0; j < 4; ++j) mx[j] = fmaxf(mx[j], mx[j + 4]);
    float sm = fmaxf(fmaxf(mx[0], mx[1]), fmaxf(mx[2], mx[3]));
    sm = fmaxf(sm, __shfl_xor(sm, 32));
    if (!__all(sm <= M + 11.5f)) {          // defer-max (T13, 8 nats)
      float Mn = fmaxf(M, sm);
      float scl = exp2_f(M - Mn);
      M = Mn;
      L *= scl;
#pragma unroll
      for (int it = 0; it < 4; ++it)
#pragma unroll
        for (int e = 0; e < 16; ++e) o[it][e] *= scl;
    }
    float pr[16];
#pragma unroll
    for (int e = 0; e < 16; ++e) pr[e] = exp2_f(st[e] - M);
    float sv[8];
#pragma unroll
    for (int j = 0; j < 8; ++j) sv[j] = pr[j] + pr[j + 8];
#pragma unroll
    for (int j = 0; j < 4; ++j) sv[j] += sv[j + 4];
    float ls = (sv[0] + sv[1]) + (sv[2] + sv[3]);
    ls += __shfl_xor(ls, 32);
    L += ls;

    // ---- P^T -> B-fragments: cvt_pk + v_permlane32_swap ------------------
    short8 pf[2];
#pragma unroll
    for (int kt = 0; kt < 2; ++kt) {
      unsigned a0 = cvt_pk(pr[kt * 8 + 0], pr[kt * 8 + 1]);
      unsigned a1 = cvt_pk(pr[kt * 8 + 2], pr[kt * 8 + 3]);
      unsigned a2 = cvt_pk(pr[kt * 8 + 4], pr[kt * 8 + 5]);
      unsigned a3 = cvt_pk(pr[kt * 8 + 6], pr[kt * 8 + 7]);
      asm volatile("v_permlane32_swap_b32 %0, %1" : "+v"(a0), "+v"(a2));
      asm volatile("v_permlane32_swap_b32 %0, %1" : "+v"(a1), "+v"(a3));
      union { unsigned u[4]; short8 s; } w;
      w.u[0] = a0; w.u[1] = a1; w.u[2] = a2; w.u[3] = a3;
      pf[kt] = w.s;
    }

    // V(t) landed (12 newer loads outstanding); sync both waves, then PV.
    asm volatile("s_waitcnt vmcnt(12)\n\ts_barrier" ::: "memory");

    // ---- Ot += Vt . P^T ---------------------------------------------------
    __builtin_amdgcn_s_setprio(1);
#pragma unroll
    for (int it = 0; it < 4; ++it) {
#pragma unroll
      for (int kt = 0; kt < 2; ++kt) {
        short8 vf = *(const short8*)(vbuf + voff[it * 2 + kt]);
        o[it] = __builtin_amdgcn_mfma_f32_32x32x16_bf16(vf, pf[kt], o[it], 0, 0, 0);
      }
    }
    __builtin_amdgcn_s_setprio(0);

    kr = (kr == 2) ? 0 : kr + 1;
    vr ^= 1;
  }
#undef STAGE_K
#undef STAGE_V

  // ---- store unnormalized partial O (fragment-order) + (M,L) --------------
  {
    const int sb2 = ms * 4 + b;
    unsigned short* Ob = Op + (size_t)sb2 * (16 * NTOK * 8);
#pragma unroll
    for (int it = 0; it < 4; ++it)
#pragma unroll
      for (int g2 = 0; g2 < 4; ++g2) {
        uint2 u2 = make_uint2(cvt_pk(o[it][4 * g2 + 0], o[it][4 * g2 + 1]),
                              cvt_pk(o[it][4 * g2 + 2], o[it][4 * g2 + 3]));
        *(uint2*)&Ob[((size_t)(it * 4 + g2) * NTOK + n0 + c32) * 8 + 4 * hl] = u2;
      }
    if (hl == 0) ML[(size_t)sb2 * NTOK + n0 + c32] = make_float2(M, L);
  }
}

// ---------------------------------------------------------------------------
// Phase 3: fused 4-split combine + out proj + residual, MFMA (unchanged).
// ---------------------------------------------------------------------------
__global__ __launch_bounds__(256) void out_kernel(
    const float* __restrict__ x, const unsigned short* __restrict__ Wb,
    const unsigned short* __restrict__ Op, const float2* __restrict__ ML,
    float* __restrict__ out)
{
  const int b = blockIdx.y;
  const int n0 = blockIdx.x * 32;
  const int t = threadIdx.x;
  const int lane = t & 63;
  const int wv = __builtin_amdgcn_readfirstlane(t >> 6);
  const int cl = lane & 15, g = lane >> 4;

  float ws4[2][4];
#pragma unroll
  for (int nsb = 0; nsb < 2; ++nsb) {
    int n = n0 + nsb * 16 + cl;
    float2 m0 = ML[(size_t)(0 * 4 + b) * NTOK + n];
    float2 m1 = ML[(size_t)(1 * 4 + b) * NTOK + n];
    float2 m2 = ML[(size_t)(2 * 4 + b) * NTOK + n];
    float2 m3 = ML[(size_t)(3 * 4 + b) * NTOK + n];
    float Mx = fmaxf(fmaxf(m0.x, m1.x), fmaxf(m2.x, m3.x));
    float w0 = exp2_f(m0.x - Mx), w1 = exp2_f(m1.x - Mx);
    float w2 = exp2_f(m2.x - Mx), w3 = exp2_f(m3.x - Mx);
    float rinv = 1.f / (w0 * m0.y + w1 * m1.y + w2 * m2.y + w3 * m3.y);
    ws4[nsb][0] = w0 * rinv; ws4[nsb][1] = w1 * rinv;
    ws4[nsb][2] = w2 * rinv; ws4[nsb][3] = w3 * rinv;
  }

  f32x4 acc[4][2];
#pragma unroll
  for (int cs = 0; cs < 4; ++cs)
#pragma unroll
    for (int nsb = 0; nsb < 2; ++nsb) acc[cs][nsb] = (f32x4){0.f, 0.f, 0.f, 0.f};

#pragma unroll
  for (int kc = 0; kc < 4; ++kc) {
    short8 bf[2];
#pragma unroll
    for (int nsb = 0; nsb < 2; ++nsb) {
      int n = n0 + nsb * 16 + cl;
      size_t base = ((size_t)(kc * 4 + g) * NTOK + n) * 8;
      const short8 f0 = *(const short8*)&Op[(size_t)(0 * 4 + b) * (16 * NTOK * 8) + base];
      const short8 f1 = *(const short8*)&Op[(size_t)(1 * 4 + b) * (16 * NTOK * 8) + base];
      const short8 f2 = *(const short8*)&Op[(size_t)(2 * 4 + b) * (16 * NTOK * 8) + base];
      const short8 f3 = *(const short8*)&Op[(size_t)(3 * 4 + b) * (16 * NTOK * 8) + base];
      float a[8];
#pragma unroll
      for (int e = 0; e < 8; ++e)
        a[e] = ws4[nsb][0] * bf2f((unsigned short)f0[e]) +
               ws4[nsb][1] * bf2f((unsigned short)f1[e]) +
               ws4[nsb][2] * bf2f((unsigned short)f2[e]) +
               ws4[nsb][3] * bf2f((unsigned short)f3[e]);
      union { unsigned u[4]; short8 s; } r;
#pragma unroll
      for (int jp = 0; jp < 4; ++jp) r.u[jp] = cvt_pk(a[2 * jp], a[2 * jp + 1]);
      bf[nsb] = r.s;
    }
#pragma unroll
    for (int cs = 0; cs < 4; ++cs) {
      short8 af = *(const short8*)&Wb[98304 +
          (((size_t)(kc * 4 + g)) * 256 + wv * 64 + cs * 16 + cl) * 8];
#pragma unroll
      for (int nsb = 0; nsb < 2; ++nsb)
        acc[cs][nsb] = __builtin_amdgcn_mfma_f32_16x16x32_bf16(af, bf[nsb], acc[cs][nsb], 0, 0, 0);
    }
  }

  const float* xb = x + (size_t)b * CDIM * NTOK;
  float* ob = out + (size_t)b * CDIM * NTOK;
#pragma unroll
  for (int cs = 0; cs < 4; ++cs)
#pragma unroll
    for (int nsb = 0; nsb < 2; ++nsb)
#pragma unroll
      for (int r = 0; r < 4; ++r) {
        int c = wv * 64 + cs * 16 + g * 4 + r;
        int n = n0 + nsb * 16 + cl;
        ob[(size_t)c * NTOK + n] = xb[(size_t)c * NTOK + n] + acc[cs][nsb][r];
      }
}

extern "C" void kernel_launch(void* const* d_in, const int* in_sizes, int n_in,
                              void* d_out, int out_size, void* d_ws, size_t ws_size,
                              hipStream_t stream) {
  const float* x  = (const float*)d_in[0];
  const float* wt = (const float*)d_in[1];
  const float* wp = (const float*)d_in[2];
  const float* wg = (const float*)d_in[3];
  const float* wo = (const float*)d_in[4];
  float* outp = (float*)d_out;

  char* ws = (char*)d_ws;
  unsigned short* Wb  = (unsigned short*)(ws);                          // 256KB
  unsigned short* Qd  = (unsigned short*)(ws + (size_t)1  * (1 << 20)); // 4MB
  unsigned short* Kd  = (unsigned short*)(ws + (size_t)5  * (1 << 20)); // 4MB
  unsigned short* Vtd = (unsigned short*)(ws + (size_t)9  * (1 << 20)); // 4MB
  unsigned short* Opd = (unsigned short*)(ws + (size_t)13 * (1 << 20)); // 16MB
  float2* MLd         = (float2*)(ws + (size_t)29 * (1 << 20));         // 512KB

  cast_w_kernel<<<128, 256, 0, stream>>>(wt, wp, wg, wo, Wb);
  qkv_kernel<<<dim3(64, BATCH), 768, 0, stream>>>(x, Wb, Qd, Kd, Vtd);
  attn_kernel<<<1024, 128, 0, stream>>>(Qd, Kd, Vtd, Opd, MLd);
  out_kernel<<<dim3(128, BATCH), 256, 0, stream>>>(x, Wb, Opd, MLd, outp);
}